// Round 20
// baseline (113.420 us; speedup 1.0000x reference)
//
#include <hip/hip_runtime.h>

typedef __bf16 bf16x8 __attribute__((ext_vector_type(8)));
typedef float f32x4 __attribute__((ext_vector_type(4)));

#define GLDS(gp, lp) __builtin_amdgcn_global_load_lds( \
    (const __attribute__((address_space(1))) void*)(gp), \
    (__attribute__((address_space(3))) void*)(lp), 16, 0, 0)
#define WAITV(n) asm volatile("s_waitcnt vmcnt(" #n ")" ::: "memory")
#define MEMF() asm volatile("" ::: "memory")

__device__ __forceinline__ unsigned short f2bf(float f) {
    unsigned int u = __builtin_bit_cast(unsigned int, f);
    u += 0x7fffu + ((u >> 16) & 1u);
    return (unsigned short)(u >> 16);
}

// ---- Fused prep: style (0..3), border-zero (4..133), packw (134..261) ----
// wpk3 layout: [mt 0..3][s=ic*9+r][wslot 0..7 = wm*4+fm][lane][8ch]
__global__ __launch_bounds__(512) void k_prep(const float* __restrict__ style,
                                              const float* __restrict__ aw,
                                              const float* __restrict__ ab,
                                              const float* __restrict__ wsrc,
                                              float* __restrict__ s_eff,
                                              unsigned short* __restrict__ xmod,
                                              unsigned short* __restrict__ wpk3) {
    __shared__ unsigned short stg[18432];
    int bid = blockIdx.x, t = threadIdx.x;
    if (bid < 4) {
        int b = bid, i = t;
        __shared__ float st[512];
        st[i] = style[(b << 9) + i];
        __syncthreads();
        const float4* row = (const float4*)(aw + ((size_t)i << 9));
        float acc = 0.f;
#pragma unroll 4
        for (int k = 0; k < 128; ++k) {
            float4 r = row[k];
            acc += r.x * st[4 * k] + r.y * st[4 * k + 1] + r.z * st[4 * k + 2] + r.w * st[4 * k + 3];
        }
        float s = acc * 0.04419417382415922f + ab[i];
        s_eff[(b << 9) + i] = s * 0.014731391274719739f;
    } else if (bid < 134) {
        int idx = (bid - 4) * 512 + t;
        int cell = idx >> 6, sub = idx & 63;
        int b = cell / 260, c = cell - b * 260;
        int row, col;
        if (c < 66)       { row = 0;  col = c; }
        else if (c < 132) { row = 65; col = c - 66; }
        else { int d = c - 132; row = 1 + (d >> 1); col = (d & 1) * 65; }
        uint4 z; z.x = z.y = z.z = z.w = 0u;
        *(uint4*)(xmod + (((size_t)(b * 66 + row) * 66 + col) << 9) + (sub << 3)) = z;
    } else {
        int blk = bid - 134;
        int mt = blk >> 5, rem = blk & 31, ic = rem >> 1, half = rem & 1;
        int o_l = t >> 3, c8 = t & 7;
        const float4* src4 = (const float4*)(wsrc + (size_t)((mt << 7) + (half << 6) + o_l) * 4608 + ic * 288);
        int wsl = o_l >> 4, lm = o_l & 15;
#pragma unroll
        for (int q = 0; q < 9; ++q) {
            float4 v = src4[c8 + (q << 3)];
            int e0 = (c8 + (q << 3)) << 2;
#pragma unroll
            for (int c = 0; c < 4; ++c) {
                int e = e0 + c;
                int il = e / 9, r = e - il * 9;
                int lk = il >> 3, j = il & 7;
                float fv = (c == 0) ? v.x : (c == 1) ? v.y : (c == 2) ? v.z : v.w;
                stg[r * 2048 + wsl * 512 + ((lk << 4) + lm) * 8 + j] = f2bf(fv);
            }
        }
        __syncthreads();
        unsigned short* dst = wpk3 + (((size_t)(mt * 144 + ic * 9)) << 12) + (half << 11);
#pragma unroll
        for (int q5 = 0; q5 < 5; ++q5) {
            int v = (q5 << 9) + t;
            if (v < 2304) {
                int q = v >> 8, word = v & 255;
                *(uint4*)(dst + (q << 12) + word * 8) = *(const uint4*)(stg + v * 8);
            }
        }
    }
}

// ---- packx ----
__global__ __launch_bounds__(256) void k_packx(const float* __restrict__ x,
                                               const float* __restrict__ s_eff,
                                               unsigned short* __restrict__ xmod) {
    int b = blockIdx.z, h = blockIdx.y, i0 = blockIdx.x << 6;
    __shared__ unsigned short tile[64][72];
    int t = threadIdx.x;
    int wq = t & 15;
    int ch = t >> 4;
#pragma unroll
    for (int p = 0; p < 4; ++p) {
        int il = (p << 4) + ch;
        int i = i0 + il;
        float4 v = *(const float4*)(x + (size_t)((((b << 9) + i) << 6) + h) * 64 + (wq << 2));
        float s = s_eff[(b << 9) + i];
        union { unsigned short us[4]; uint2 u2; } u;
        u.us[0] = f2bf(v.x * s); u.us[1] = f2bf(v.y * s);
        u.us[2] = f2bf(v.z * s); u.us[3] = f2bf(v.w * s);
        *(uint2*)&tile[il][wq << 2] = u.u2;
    }
    __syncthreads();
    int ib = (t & 7) << 3;
    int wb = t >> 3;
#pragma unroll
    for (int pass = 0; pass < 2; ++pass) {
        int w = wb + (pass << 5);
        union { unsigned short us[8]; uint4 v; } u;
#pragma unroll
        for (int j = 0; j < 8; ++j) u.us[j] = tile[ib + j][w];
        *(uint4*)(xmod + (((size_t)(b * 66 + h + 1) * 66 + (w + 1)) << 9) + i0 + ib) = u.v;
    }
}

// ---- k_conv: R19 base + PHASE-SPLIT step (T3 mechanism): each K-step's 16 MFMAs
// become two barrier-separated half-clusters; phase0 carries af(s+2) global issues,
// phase1 carries bfr(s+1) ds_reads + the r==4 B-GLDS batch. vmcnt ledger identical
// to R19 (issue points unchanged; barriers only add alignment). ----
__global__ __launch_bounds__(256, 2) void k_conv(const unsigned short* __restrict__ xmod,
                                                 const unsigned short* __restrict__ wpk3,
                                                 float* __restrict__ out) {
    __shared__ __attribute__((aligned(128))) unsigned char lds[2][17408];

    int bid = blockIdx.x;
    int swz = ((bid & 7) << 6) | (bid >> 3);
    int mt = swz >> 7, nt = swz & 127;
    int b = nt >> 5, h0 = (nt & 31) << 1;
    int m0 = mt << 7;
    int tid = threadIdx.x;
    int lane = tid & 63;
    int wv = tid >> 6;
    int wave_m = wv & 1, wave_n = wv >> 1;
    int lm = lane & 15, lk = lane >> 4;

    const unsigned char* xq = (const unsigned char*)xmod;

    int bsrc[5];
#pragma unroll
    for (int q = 0; q < 5; ++q) {
        int c = q * 256 + tid; if (c > 1055) c = 1055;
        int cl = c >> 2, sub = c & 3;
        int row = cl / 66, col = cl - row * 66;
        int sub2 = sub ^ ((col >> 1) & 3);
        bsrc[q] = ((b * 66 + h0 + row) * 66 + col) * 1024 + (sub2 << 4);
    }

    int boff[4][3];
#pragma unroll
    for (int fn = 0; fn < 4; ++fn) {
        int nl = (wave_n << 6) + (fn << 4) + lm;
        int hl = nl >> 6, w = nl & 63;
#pragma unroll
        for (int kw = 0; kw < 3; ++kw) {
            int col = w + kw;
            boff[fn][kw] = hl * 4224 + col * 64 + ((lk ^ ((col >> 1) & 3)) << 4);
        }
    }

    const unsigned short* abase = wpk3 + ((size_t)mt * 144) * 4096 + ((wave_m << 2) << 9) + (lane << 3);

    f32x4 acc[4][4] = {};
    bf16x8 af[3][4];
    bf16x8 bfr[2][4];

    {
        unsigned char* bd = &lds[0][0] + wv * 1024;
        GLDS(xq + bsrc[0], bd);
        GLDS(xq + bsrc[1], bd + 4096);
        GLDS(xq + bsrc[2], bd + 8192);
        GLDS(xq + bsrc[3], bd + 12288);
        if (wv == 0) GLDS(xq + bsrc[4], &lds[0][0] + 16384);
    }
#pragma unroll
    for (int s = 0; s < 2; ++s)
#pragma unroll
        for (int fm = 0; fm < 4; ++fm)
            af[s][fm] = *(const bf16x8*)(abase + s * 4096 + fm * 512);

#pragma unroll 1
    for (int ic = 0; ic < 16; ++ic) {
        const unsigned char* Bb = &lds[ic & 1][0];
        unsigned char* Bn = &lds[(ic + 1) & 1][0];
#pragma unroll
        for (int r = 0; r < 9; ++r) {
            if (r == 0) {
                WAITV(4);
                __builtin_amdgcn_s_barrier();
                MEMF();
                // own-step bfr (r=0: kh=0,kw=0) right after chunk barrier
#pragma unroll
                for (int fn = 0; fn < 4; ++fn)
                    bfr[0][fn] = *(const bf16x8*)(Bb + boff[fn][0]);
            }
            int s = ic * 9 + r;
            // ---- phase 0: issue af(s+2) global loads, then half MFMA (fm 0,1) ----
            {
                const unsigned short* ap = abase + (size_t)(s + 2) * 4096;
#pragma unroll
                for (int fm = 0; fm < 4; ++fm)
                    af[(r + 2) % 3][fm] = *(const bf16x8*)(ap + fm * 512);
            }
            __builtin_amdgcn_s_barrier();
            __builtin_amdgcn_s_setprio(1);
#pragma unroll
            for (int fm = 0; fm < 2; ++fm)
#pragma unroll
                for (int fn = 0; fn < 4; ++fn)
                    acc[fm][fn] = __builtin_amdgcn_mfma_f32_16x16x32_bf16(af[r % 3][fm], bfr[r & 1][fn], acc[fm][fn], 0, 0, 0);
            __builtin_amdgcn_s_setprio(0);
            MEMF();
            // ---- phase 1: bfr(s+1) ds_reads (+ B-GLDS at r==4), then half MFMA (fm 2,3) ----
            if (r == 4) {
                int icb = (ic + 1) << 6;
                unsigned char* bd = Bn + wv * 1024;
                GLDS(xq + bsrc[0] + icb, bd);
                GLDS(xq + bsrc[1] + icb, bd + 4096);
                GLDS(xq + bsrc[2] + icb, bd + 8192);
                GLDS(xq + bsrc[3] + icb, bd + 12288);
                if (wv == 0) GLDS(xq + bsrc[4] + icb, Bn + 16384);
            }
            if (r < 8) {
                int r1 = r + 1;
                int kh1 = r1 / 3, kw1 = r1 - kh1 * 3;
#pragma unroll
                for (int fn = 0; fn < 4; ++fn)
                    bfr[(r + 1) & 1][fn] = *(const bf16x8*)(Bb + boff[fn][kw1] + kh1 * 4224);
            }
            __builtin_amdgcn_s_barrier();
            __builtin_amdgcn_s_setprio(1);
#pragma unroll
            for (int fm = 2; fm < 4; ++fm)
#pragma unroll
                for (int fn = 0; fn < 4; ++fn)
                    acc[fm][fn] = __builtin_amdgcn_mfma_f32_16x16x32_bf16(af[r % 3][fm], bfr[r & 1][fn], acc[fm][fn], 0, 0, 0);
            __builtin_amdgcn_s_setprio(0);
            MEMF();
        }
    }

#pragma unroll
    for (int fm = 0; fm < 4; ++fm) {
        int o = m0 + (wave_m << 6) + (fm << 4) + (lk << 2);
#pragma unroll
        for (int fn = 0; fn < 4; ++fn) {
            int nl = (wave_n << 6) + (fn << 4) + lm;
            int hl = nl >> 6, w = nl & 63;
            float* dst = out + ((((b << 9) + o) << 6) + (h0 + hl)) * 64 + w;
#pragma unroll
            for (int rr = 0; rr < 4; ++rr)
                dst[rr * 4096] = acc[fm][fn][rr];
        }
    }
}

extern "C" void kernel_launch(void* const* d_in, const int* in_sizes, int n_in,
                              void* d_out, int out_size, void* d_ws, size_t ws_size,
                              hipStream_t stream) {
    const float* x      = (const float*)d_in[0];
    const float* style  = (const float*)d_in[1];
    const float* weight = (const float*)d_in[2];
    const float* aff_w  = (const float*)d_in[3];
    const float* aff_b  = (const float*)d_in[4];
    float* out = (float*)d_out;

    unsigned short* xmod = (unsigned short*)d_ws;            // 17,842,176 B
    unsigned short* wpk3 = xmod + 8921088;                   // 4,718,592 B (+16KB tail slack)
    float* s_eff = (float*)((char*)d_ws + 22577152);         // 2048 f32

    hipLaunchKernelGGL(k_prep, dim3(262), dim3(512), 0, stream,
                       style, aff_w, aff_b, weight, s_eff, xmod, wpk3);
    hipLaunchKernelGGL(k_packx, dim3(8, 64, 4), dim3(256), 0, stream, x, s_eff, xmod);
    hipLaunchKernelGGL(k_conv, dim3(512), dim3(256), 0, stream, xmod, wpk3, out);
}

// Round 21
// 105.805 us; speedup vs baseline: 1.0720x; 1.0720x over previous
//
#include <hip/hip_runtime.h>

typedef __bf16 bf16x8 __attribute__((ext_vector_type(8)));
typedef float f32x4 __attribute__((ext_vector_type(4)));

#define GLDS(gp, lp) __builtin_amdgcn_global_load_lds( \
    (const __attribute__((address_space(1))) void*)(gp), \
    (__attribute__((address_space(3))) void*)(lp), 16, 0, 0)
#define WAITV(n) asm volatile("s_waitcnt vmcnt(" #n ")" ::: "memory")
#define MEMF() asm volatile("" ::: "memory")

__device__ __forceinline__ unsigned short f2bf(float f) {
    unsigned int u = __builtin_bit_cast(unsigned int, f);
    u += 0x7fffu + ((u >> 16) & 1u);
    return (unsigned short)(u >> 16);
}

// ---- K1: fused pack. blocks 0..129 border-zero, 130..257 packw, 258..2305 packx
// (packx computes its 64 s_eff values INLINE: style dot against L2-resident affine_w).
// wpk3 layout: [mt 0..3][s=ic*9+r][wslot 0..7 = wm*4+fm][lane][8ch]
__global__ __launch_bounds__(512) void k_pack(const float* __restrict__ x,
                                              const float* __restrict__ style,
                                              const float* __restrict__ aw,
                                              const float* __restrict__ ab,
                                              const float* __restrict__ wsrc,
                                              unsigned short* __restrict__ xmod,
                                              unsigned short* __restrict__ wpk3) {
    __shared__ __attribute__((aligned(16))) unsigned char shraw[36864];
    int bid = blockIdx.x, t = threadIdx.x;
    if (bid < 130) {
        // border-zero: 4*260 cells * 64 ch-chunks = 66560 items
        int idx = bid * 512 + t;
        int cell = idx >> 6, sub = idx & 63;
        int b = cell / 260, c = cell - b * 260;
        int row, col;
        if (c < 66)       { row = 0;  col = c; }
        else if (c < 132) { row = 65; col = c - 66; }
        else { int d = c - 132; row = 1 + (d >> 1); col = (d & 1) * 65; }
        uint4 z; z.x = z.y = z.z = z.w = 0u;
        *(uint4*)(xmod + (((size_t)(b * 66 + row) * 66 + col) << 9) + (sub << 3)) = z;
    } else if (bid < 258) {
        // packw: per block (mt, ic, half); 64 o-rows x 288 f32
        unsigned short* stg = (unsigned short*)shraw;   // 18432 ushort
        int blk = bid - 130;
        int mt = blk >> 5, rem = blk & 31, ic = rem >> 1, half = rem & 1;
        int o_l = t >> 3, c8 = t & 7;
        const float4* src4 = (const float4*)(wsrc + (size_t)((mt << 7) + (half << 6) + o_l) * 4608 + ic * 288);
        int wsl = o_l >> 4, lm = o_l & 15;
#pragma unroll
        for (int q = 0; q < 9; ++q) {
            float4 v = src4[c8 + (q << 3)];
            int e0 = (c8 + (q << 3)) << 2;
#pragma unroll
            for (int c = 0; c < 4; ++c) {
                int e = e0 + c;
                int il = e / 9, r = e - il * 9;
                int lk = il >> 3, j = il & 7;
                float fv = (c == 0) ? v.x : (c == 1) ? v.y : (c == 2) ? v.z : v.w;
                stg[r * 2048 + wsl * 512 + ((lk << 4) + lm) * 8 + j] = f2bf(fv);
            }
        }
        __syncthreads();
        unsigned short* dst = wpk3 + (((size_t)(mt * 144 + ic * 9)) << 12) + (half << 11);
#pragma unroll
        for (int q5 = 0; q5 < 5; ++q5) {
            int v = (q5 << 9) + t;
            if (v < 2304) {
                int q = v >> 8, word = v & 255;
                *(uint4*)(dst + (q << 12) + word * 8) = *(const uint4*)(stg + v * 8);
            }
        }
    } else {
        // packx: per block (b, h, i0); inline style for 64 channels
        unsigned short (*tile)[72] = (unsigned short(*)[72])shraw;  // 9216 B
        float* st   = (float*)(shraw + 9728);    // 512 f32
        float* part = (float*)(shraw + 11776);   // 64x8 f32
        float* s_sh = (float*)(shraw + 13824);   // 64 f32
        int pb = bid - 258;
        int ix = pb & 7, h = (pb >> 3) & 63, b = pb >> 9;
        int i0 = ix << 6;
        // --- style dot: s_eff[b][i0+l] for l=0..63 ---
        st[t] = style[(b << 9) + t];
        __syncthreads();
        {
            int row = t >> 3, seg = t & 7;
            const float4* ap4 = (const float4*)(aw + (size_t)(i0 + row) * 512 + (seg << 6));
            float acc = 0.f;
#pragma unroll
            for (int k = 0; k < 16; ++k) {
                float4 v = ap4[k];
                int e = (seg << 6) + (k << 2);
                acc += v.x * st[e] + v.y * st[e + 1] + v.z * st[e + 2] + v.w * st[e + 3];
            }
            part[(row << 3) + seg] = acc;
        }
        __syncthreads();
        if (t < 64) {
            float s = 0.f;
#pragma unroll
            for (int g = 0; g < 8; ++g) s += part[(t << 3) + g];
            s = s * 0.04419417382415922f + ab[i0 + t];     // 1/sqrt(512)
            s_sh[t] = s * 0.014731391274719739f;           // * 1/sqrt(512*9)
        }
        __syncthreads();
        // --- modulate + transpose to NHWC ---
        int wq = t & 15, chh = t >> 4;                      // chh 0..31
#pragma unroll
        for (int p = 0; p < 2; ++p) {
            int il = (p << 5) + chh;
            int i = i0 + il;
            float4 v = *(const float4*)(x + (size_t)((((b << 9) + i) << 6) + h) * 64 + (wq << 2));
            float s = s_sh[il];
            union { unsigned short us[4]; uint2 u2; } u;
            u.us[0] = f2bf(v.x * s); u.us[1] = f2bf(v.y * s);
            u.us[2] = f2bf(v.z * s); u.us[3] = f2bf(v.w * s);
            *(uint2*)&tile[il][wq << 2] = u.u2;
        }
        __syncthreads();
        int ib = (t & 7) << 3, wb = t >> 3;                 // wb 0..63
        union { unsigned short us[8]; uint4 v; } u;
#pragma unroll
        for (int j = 0; j < 8; ++j) u.us[j] = tile[ib + j][wb];
        *(uint4*)(xmod + (((size_t)(b * 66 + h + 1) * 66 + (wb + 1)) << 9) + i0 + ib) = u.v;
    }
}

// ---- k_conv: R19 EXACT (best measured 69.5 us) ----
__global__ __launch_bounds__(256, 2) void k_conv(const unsigned short* __restrict__ xmod,
                                                 const unsigned short* __restrict__ wpk3,
                                                 float* __restrict__ out) {
    __shared__ __attribute__((aligned(128))) unsigned char lds[2][17408];

    int bid = blockIdx.x;
    int swz = ((bid & 7) << 6) | (bid >> 3);
    int mt = swz >> 7, nt = swz & 127;
    int b = nt >> 5, h0 = (nt & 31) << 1;
    int m0 = mt << 7;
    int tid = threadIdx.x;
    int lane = tid & 63;
    int wv = tid >> 6;
    int wave_m = wv & 1, wave_n = wv >> 1;
    int lm = lane & 15, lk = lane >> 4;

    const unsigned char* xq = (const unsigned char*)xmod;

    int bsrc[5];
#pragma unroll
    for (int q = 0; q < 5; ++q) {
        int c = q * 256 + tid; if (c > 1055) c = 1055;
        int cl = c >> 2, sub = c & 3;
        int row = cl / 66, col = cl - row * 66;
        int sub2 = sub ^ ((col >> 1) & 3);
        bsrc[q] = ((b * 66 + h0 + row) * 66 + col) * 1024 + (sub2 << 4);
    }

    int boff[4][3];
#pragma unroll
    for (int fn = 0; fn < 4; ++fn) {
        int nl = (wave_n << 6) + (fn << 4) + lm;
        int hl = nl >> 6, w = nl & 63;
#pragma unroll
        for (int kw = 0; kw < 3; ++kw) {
            int col = w + kw;
            boff[fn][kw] = hl * 4224 + col * 64 + ((lk ^ ((col >> 1) & 3)) << 4);
        }
    }

    const unsigned short* abase = wpk3 + ((size_t)mt * 144) * 4096 + ((wave_m << 2) << 9) + (lane << 3);

    f32x4 acc[4][4] = {};
    bf16x8 af[3][4];
    bf16x8 bfr[2][4];

    {
        unsigned char* bd = &lds[0][0] + wv * 1024;
        GLDS(xq + bsrc[0], bd);
        GLDS(xq + bsrc[1], bd + 4096);
        GLDS(xq + bsrc[2], bd + 8192);
        GLDS(xq + bsrc[3], bd + 12288);
        if (wv == 0) GLDS(xq + bsrc[4], &lds[0][0] + 16384);
    }
#pragma unroll
    for (int s = 0; s < 2; ++s)
#pragma unroll
        for (int fm = 0; fm < 4; ++fm)
            af[s][fm] = *(const bf16x8*)(abase + s * 4096 + fm * 512);

#pragma unroll 1
    for (int ic = 0; ic < 16; ++ic) {
        const unsigned char* Bb = &lds[ic & 1][0];
        unsigned char* Bn = &lds[(ic + 1) & 1][0];
#pragma unroll
        for (int r = 0; r < 9; ++r) {
            if (r == 0) {
                WAITV(4);
                __builtin_amdgcn_s_barrier();
                MEMF();
#pragma unroll
                for (int fn = 0; fn < 4; ++fn)
                    bfr[0][fn] = *(const bf16x8*)(Bb + boff[fn][0]);
            }
            int s = ic * 9 + r;
            {
                const unsigned short* ap = abase + (size_t)(s + 2) * 4096;
#pragma unroll
                for (int fm = 0; fm < 4; ++fm)
                    af[(r + 2) % 3][fm] = *(const bf16x8*)(ap + fm * 512);
            }
            if (r == 4) {
                int icb = (ic + 1) << 6;
                unsigned char* bd = Bn + wv * 1024;
                GLDS(xq + bsrc[0] + icb, bd);
                GLDS(xq + bsrc[1] + icb, bd + 4096);
                GLDS(xq + bsrc[2] + icb, bd + 8192);
                GLDS(xq + bsrc[3] + icb, bd + 12288);
                if (wv == 0) GLDS(xq + bsrc[4] + icb, Bn + 16384);
            }
            if (r < 8) {
                int r1 = r + 1;
                int kh1 = r1 / 3, kw1 = r1 - kh1 * 3;
#pragma unroll
                for (int fn = 0; fn < 4; ++fn)
                    bfr[(r + 1) & 1][fn] = *(const bf16x8*)(Bb + boff[fn][kw1] + kh1 * 4224);
            }
            __builtin_amdgcn_s_setprio(1);
#pragma unroll
            for (int fm = 0; fm < 4; ++fm)
#pragma unroll
                for (int fn = 0; fn < 4; ++fn)
                    acc[fm][fn] = __builtin_amdgcn_mfma_f32_16x16x32_bf16(af[r % 3][fm], bfr[r & 1][fn], acc[fm][fn], 0, 0, 0);
            __builtin_amdgcn_s_setprio(0);
            MEMF();
        }
    }

#pragma unroll
    for (int fm = 0; fm < 4; ++fm) {
        int o = m0 + (wave_m << 6) + (fm << 4) + (lk << 2);
#pragma unroll
        for (int fn = 0; fn < 4; ++fn) {
            int nl = (wave_n << 6) + (fn << 4) + lm;
            int hl = nl >> 6, w = nl & 63;
            float* dst = out + ((((b << 9) + o) << 6) + (h0 + hl)) * 64 + w;
#pragma unroll
            for (int rr = 0; rr < 4; ++rr)
                dst[rr * 4096] = acc[fm][fn][rr];
        }
    }
}

extern "C" void kernel_launch(void* const* d_in, const int* in_sizes, int n_in,
                              void* d_out, int out_size, void* d_ws, size_t ws_size,
                              hipStream_t stream) {
    const float* x      = (const float*)d_in[0];
    const float* style  = (const float*)d_in[1];
    const float* weight = (const float*)d_in[2];
    const float* aff_w  = (const float*)d_in[3];
    const float* aff_b  = (const float*)d_in[4];
    float* out = (float*)d_out;

    unsigned short* xmod = (unsigned short*)d_ws;            // 17,842,176 B
    unsigned short* wpk3 = xmod + 8921088;                   // 4,718,592 B (+16KB tail slack)

    hipLaunchKernelGGL(k_pack, dim3(2306), dim3(512), 0, stream,
                       x, style, aff_w, aff_b, weight, xmod, wpk3);
    hipLaunchKernelGGL(k_conv, dim3(512), dim3(256), 0, stream, xmod, wpk3, out);
}

// Round 22
// 86.485 us; speedup vs baseline: 1.3114x; 1.2234x over previous
//
#include <hip/hip_runtime.h>

typedef __bf16 bf16x8 __attribute__((ext_vector_type(8)));
typedef float f32x4 __attribute__((ext_vector_type(4)));

#define GLDS(gp, lp) __builtin_amdgcn_global_load_lds( \
    (const __attribute__((address_space(1))) void*)(gp), \
    (__attribute__((address_space(3))) void*)(lp), 16, 0, 0)
#define WAITV(n) asm volatile("s_waitcnt vmcnt(" #n ")" ::: "memory")
#define MEMF() asm volatile("" ::: "memory")

__device__ __forceinline__ unsigned short f2bf(float f) {
    unsigned int u = __builtin_bit_cast(unsigned int, f);
    u += 0x7fffu + ((u >> 16) & 1u);
    return (unsigned short)(u >> 16);
}

// ---- K1: fused pack. blocks 0..255 packx (8 h-rows each), 256..383 packw, 384..513 border.
// packx: block (b, ix, hg) covers h = hg*8..hg*8+7; style dot computed ONCE per block
// (shuffle-reduced), then 8x modulate+transpose. wpk3: [mt][s=ic*9+r][wslot][lane][8ch]
__global__ __launch_bounds__(512) void k_pack(const float* __restrict__ x,
                                              const float* __restrict__ style,
                                              const float* __restrict__ aw,
                                              const float* __restrict__ ab,
                                              const float* __restrict__ wsrc,
                                              unsigned short* __restrict__ xmod,
                                              unsigned short* __restrict__ wpk3) {
    __shared__ __attribute__((aligned(16))) unsigned char shraw[36864];
    int bid = blockIdx.x, t = threadIdx.x;
    if (bid < 256) {
        // ---- packx ----
        unsigned short (*tile)[72] = (unsigned short(*)[72])shraw;  // 9216 B
        float* st   = (float*)(shraw + 9728);    // 512 f32
        float* s_sh = (float*)(shraw + 11776);   // 64 f32
        int ix = bid & 7, hg = (bid >> 3) & 7, b = bid >> 6;
        int i0 = ix << 6;
        // style dot: s_eff[b][i0+row], row = t>>3, seg = t&7 (8 consecutive lanes per row)
        st[t] = style[(b << 9) + t];
        __syncthreads();
        {
            int row = t >> 3, seg = t & 7;
            const float4* ap4 = (const float4*)(aw + (size_t)(i0 + row) * 512 + (seg << 6));
            float acc = 0.f;
#pragma unroll
            for (int k = 0; k < 16; ++k) {
                float4 v = ap4[k];
                int e = (seg << 6) + (k << 2);
                acc += v.x * st[e] + v.y * st[e + 1] + v.z * st[e + 2] + v.w * st[e + 3];
            }
            acc += __shfl_xor(acc, 1);
            acc += __shfl_xor(acc, 2);
            acc += __shfl_xor(acc, 4);
            if (seg == 0) {
                float s = acc * 0.04419417382415922f + ab[i0 + row];   // 1/sqrt(512)
                s_sh[row] = s * 0.014731391274719739f;                  // * 1/sqrt(512*9)
            }
        }
        __syncthreads();
        int wq = t & 15, chh = t >> 4;                  // chh 0..31
        int ib = (t & 7) << 3, wb = t >> 3;             // store-pass indices
#pragma unroll 1
        for (int hh = 0; hh < 8; ++hh) {
            int h = (hg << 3) + hh;
#pragma unroll
            for (int p = 0; p < 2; ++p) {
                int il = (p << 5) + chh;
                int i = i0 + il;
                float4 v = *(const float4*)(x + (size_t)((((b << 9) + i) << 6) + h) * 64 + (wq << 2));
                float s = s_sh[il];
                union { unsigned short us[4]; uint2 u2; } u;
                u.us[0] = f2bf(v.x * s); u.us[1] = f2bf(v.y * s);
                u.us[2] = f2bf(v.z * s); u.us[3] = f2bf(v.w * s);
                *(uint2*)&tile[il][wq << 2] = u.u2;
            }
            __syncthreads();
            union { unsigned short us[8]; uint4 v; } u;
#pragma unroll
            for (int j = 0; j < 8; ++j) u.us[j] = tile[ib + j][wb];
            *(uint4*)(xmod + (((size_t)(b * 66 + h + 1) * 66 + (wb + 1)) << 9) + i0 + ib) = u.v;
            __syncthreads();
        }
    } else if (bid < 384) {
        // ---- packw: per block (mt, ic, half); 64 o-rows x 288 f32 ----
        unsigned short* stg = (unsigned short*)shraw;   // 18432 ushort
        int blk = bid - 256;
        int mt = blk >> 5, rem = blk & 31, ic = rem >> 1, half = rem & 1;
        int o_l = t >> 3, c8 = t & 7;
        const float4* src4 = (const float4*)(wsrc + (size_t)((mt << 7) + (half << 6) + o_l) * 4608 + ic * 288);
        int wsl = o_l >> 4, lm = o_l & 15;
#pragma unroll
        for (int q = 0; q < 9; ++q) {
            float4 v = src4[c8 + (q << 3)];
            int e0 = (c8 + (q << 3)) << 2;
#pragma unroll
            for (int c = 0; c < 4; ++c) {
                int e = e0 + c;
                int il = e / 9, r = e - il * 9;
                int lk = il >> 3, j = il & 7;
                float fv = (c == 0) ? v.x : (c == 1) ? v.y : (c == 2) ? v.z : v.w;
                stg[r * 2048 + wsl * 512 + ((lk << 4) + lm) * 8 + j] = f2bf(fv);
            }
        }
        __syncthreads();
        unsigned short* dst = wpk3 + (((size_t)(mt * 144 + ic * 9)) << 12) + (half << 11);
#pragma unroll
        for (int q5 = 0; q5 < 5; ++q5) {
            int v = (q5 << 9) + t;
            if (v < 2304) {
                int q = v >> 8, word = v & 255;
                *(uint4*)(dst + (q << 12) + word * 8) = *(const uint4*)(stg + v * 8);
            }
        }
    } else {
        // ---- border-zero: 4*260 cells * 64 ch-chunks = 66560 items ----
        int idx = (bid - 384) * 512 + t;
        int cell = idx >> 6, sub = idx & 63;
        int b = cell / 260, c = cell - b * 260;
        int row, col;
        if (c < 66)       { row = 0;  col = c; }
        else if (c < 132) { row = 65; col = c - 66; }
        else { int d = c - 132; row = 1 + (d >> 1); col = (d & 1) * 65; }
        uint4 z; z.x = z.y = z.z = z.w = 0u;
        *(uint4*)(xmod + (((size_t)(b * 66 + row) * 66 + col) << 9) + (sub << 3)) = z;
    }
}

// ---- k_conv: R19 EXACT (best measured 69.5 us) ----
__global__ __launch_bounds__(256, 2) void k_conv(const unsigned short* __restrict__ xmod,
                                                 const unsigned short* __restrict__ wpk3,
                                                 float* __restrict__ out) {
    __shared__ __attribute__((aligned(128))) unsigned char lds[2][17408];

    int bid = blockIdx.x;
    int swz = ((bid & 7) << 6) | (bid >> 3);
    int mt = swz >> 7, nt = swz & 127;
    int b = nt >> 5, h0 = (nt & 31) << 1;
    int m0 = mt << 7;
    int tid = threadIdx.x;
    int lane = tid & 63;
    int wv = tid >> 6;
    int wave_m = wv & 1, wave_n = wv >> 1;
    int lm = lane & 15, lk = lane >> 4;

    const unsigned char* xq = (const unsigned char*)xmod;

    int bsrc[5];
#pragma unroll
    for (int q = 0; q < 5; ++q) {
        int c = q * 256 + tid; if (c > 1055) c = 1055;
        int cl = c >> 2, sub = c & 3;
        int row = cl / 66, col = cl - row * 66;
        int sub2 = sub ^ ((col >> 1) & 3);
        bsrc[q] = ((b * 66 + h0 + row) * 66 + col) * 1024 + (sub2 << 4);
    }

    int boff[4][3];
#pragma unroll
    for (int fn = 0; fn < 4; ++fn) {
        int nl = (wave_n << 6) + (fn << 4) + lm;
        int hl = nl >> 6, w = nl & 63;
#pragma unroll
        for (int kw = 0; kw < 3; ++kw) {
            int col = w + kw;
            boff[fn][kw] = hl * 4224 + col * 64 + ((lk ^ ((col >> 1) & 3)) << 4);
        }
    }

    const unsigned short* abase = wpk3 + ((size_t)mt * 144) * 4096 + ((wave_m << 2) << 9) + (lane << 3);

    f32x4 acc[4][4] = {};
    bf16x8 af[3][4];
    bf16x8 bfr[2][4];

    {
        unsigned char* bd = &lds[0][0] + wv * 1024;
        GLDS(xq + bsrc[0], bd);
        GLDS(xq + bsrc[1], bd + 4096);
        GLDS(xq + bsrc[2], bd + 8192);
        GLDS(xq + bsrc[3], bd + 12288);
        if (wv == 0) GLDS(xq + bsrc[4], &lds[0][0] + 16384);
    }
#pragma unroll
    for (int s = 0; s < 2; ++s)
#pragma unroll
        for (int fm = 0; fm < 4; ++fm)
            af[s][fm] = *(const bf16x8*)(abase + s * 4096 + fm * 512);

#pragma unroll 1
    for (int ic = 0; ic < 16; ++ic) {
        const unsigned char* Bb = &lds[ic & 1][0];
        unsigned char* Bn = &lds[(ic + 1) & 1][0];
#pragma unroll
        for (int r = 0; r < 9; ++r) {
            if (r == 0) {
                WAITV(4);
                __builtin_amdgcn_s_barrier();
                MEMF();
#pragma unroll
                for (int fn = 0; fn < 4; ++fn)
                    bfr[0][fn] = *(const bf16x8*)(Bb + boff[fn][0]);
            }
            int s = ic * 9 + r;
            {
                const unsigned short* ap = abase + (size_t)(s + 2) * 4096;
#pragma unroll
                for (int fm = 0; fm < 4; ++fm)
                    af[(r + 2) % 3][fm] = *(const bf16x8*)(ap + fm * 512);
            }
            if (r == 4) {
                int icb = (ic + 1) << 6;
                unsigned char* bd = Bn + wv * 1024;
                GLDS(xq + bsrc[0] + icb, bd);
                GLDS(xq + bsrc[1] + icb, bd + 4096);
                GLDS(xq + bsrc[2] + icb, bd + 8192);
                GLDS(xq + bsrc[3] + icb, bd + 12288);
                if (wv == 0) GLDS(xq + bsrc[4] + icb, Bn + 16384);
            }
            if (r < 8) {
                int r1 = r + 1;
                int kh1 = r1 / 3, kw1 = r1 - kh1 * 3;
#pragma unroll
                for (int fn = 0; fn < 4; ++fn)
                    bfr[(r + 1) & 1][fn] = *(const bf16x8*)(Bb + boff[fn][kw1] + kh1 * 4224);
            }
            __builtin_amdgcn_s_setprio(1);
#pragma unroll
            for (int fm = 0; fm < 4; ++fm)
#pragma unroll
                for (int fn = 0; fn < 4; ++fn)
                    acc[fm][fn] = __builtin_amdgcn_mfma_f32_16x16x32_bf16(af[r % 3][fm], bfr[r & 1][fn], acc[fm][fn], 0, 0, 0);
            __builtin_amdgcn_s_setprio(0);
            MEMF();
        }
    }

#pragma unroll
    for (int fm = 0; fm < 4; ++fm) {
        int o = m0 + (wave_m << 6) + (fm << 4) + (lk << 2);
#pragma unroll
        for (int fn = 0; fn < 4; ++fn) {
            int nl = (wave_n << 6) + (fn << 4) + lm;
            int hl = nl >> 6, w = nl & 63;
            float* dst = out + ((((b << 9) + o) << 6) + (h0 + hl)) * 64 + w;
#pragma unroll
            for (int rr = 0; rr < 4; ++rr)
                dst[rr * 4096] = acc[fm][fn][rr];
        }
    }
}

extern "C" void kernel_launch(void* const* d_in, const int* in_sizes, int n_in,
                              void* d_out, int out_size, void* d_ws, size_t ws_size,
                              hipStream_t stream) {
    const float* x      = (const float*)d_in[0];
    const float* style  = (const float*)d_in[1];
    const float* weight = (const float*)d_in[2];
    const float* aff_w  = (const float*)d_in[3];
    const float* aff_b  = (const float*)d_in[4];
    float* out = (float*)d_out;

    unsigned short* xmod = (unsigned short*)d_ws;            // 17,842,176 B
    unsigned short* wpk3 = xmod + 8921088;                   // 4,718,592 B (+16KB tail slack)

    hipLaunchKernelGGL(k_pack, dim3(514), dim3(512), 0, stream,
                       x, style, aff_w, aff_b, weight, xmod, wpk3);
    hipLaunchKernelGGL(k_conv, dim3(512), dim3(256), 0, stream, xmod, wpk3, out);
}

// Round 23
// 85.731 us; speedup vs baseline: 1.3230x; 1.0088x over previous
//
#include <hip/hip_runtime.h>

typedef __bf16 bf16x8 __attribute__((ext_vector_type(8)));
typedef float f32x4 __attribute__((ext_vector_type(4)));

#define GLDS(gp, lp) __builtin_amdgcn_global_load_lds( \
    (const __attribute__((address_space(1))) void*)(gp), \
    (__attribute__((address_space(3))) void*)(lp), 16, 0, 0)
#define WAITV(n) asm volatile("s_waitcnt vmcnt(" #n ")" ::: "memory")
#define MEMF() asm volatile("" ::: "memory")

__device__ __forceinline__ unsigned short f2bf(float f) {
    unsigned int u = __builtin_bit_cast(unsigned int, f);
    u += 0x7fffu + ((u >> 16) & 1u);
    return (unsigned short)(u >> 16);
}

// ---- K1: fused pack (R22 exact). 0..255 packx (8 h-rows), 256..383 packw, 384..513 border.
__global__ __launch_bounds__(512) void k_pack(const float* __restrict__ x,
                                              const float* __restrict__ style,
                                              const float* __restrict__ aw,
                                              const float* __restrict__ ab,
                                              const float* __restrict__ wsrc,
                                              unsigned short* __restrict__ xmod,
                                              unsigned short* __restrict__ wpk3) {
    __shared__ __attribute__((aligned(16))) unsigned char shraw[36864];
    int bid = blockIdx.x, t = threadIdx.x;
    if (bid < 256) {
        unsigned short (*tile)[72] = (unsigned short(*)[72])shraw;
        float* st   = (float*)(shraw + 9728);
        float* s_sh = (float*)(shraw + 11776);
        int ix = bid & 7, hg = (bid >> 3) & 7, b = bid >> 6;
        int i0 = ix << 6;
        st[t] = style[(b << 9) + t];
        __syncthreads();
        {
            int row = t >> 3, seg = t & 7;
            const float4* ap4 = (const float4*)(aw + (size_t)(i0 + row) * 512 + (seg << 6));
            float acc = 0.f;
#pragma unroll
            for (int k = 0; k < 16; ++k) {
                float4 v = ap4[k];
                int e = (seg << 6) + (k << 2);
                acc += v.x * st[e] + v.y * st[e + 1] + v.z * st[e + 2] + v.w * st[e + 3];
            }
            acc += __shfl_xor(acc, 1);
            acc += __shfl_xor(acc, 2);
            acc += __shfl_xor(acc, 4);
            if (seg == 0) {
                float s = acc * 0.04419417382415922f + ab[i0 + row];
                s_sh[row] = s * 0.014731391274719739f;
            }
        }
        __syncthreads();
        int wq = t & 15, chh = t >> 4;
        int ib = (t & 7) << 3, wb = t >> 3;
#pragma unroll 1
        for (int hh = 0; hh < 8; ++hh) {
            int h = (hg << 3) + hh;
#pragma unroll
            for (int p = 0; p < 2; ++p) {
                int il = (p << 5) + chh;
                int i = i0 + il;
                float4 v = *(const float4*)(x + (size_t)((((b << 9) + i) << 6) + h) * 64 + (wq << 2));
                float s = s_sh[il];
                union { unsigned short us[4]; uint2 u2; } u;
                u.us[0] = f2bf(v.x * s); u.us[1] = f2bf(v.y * s);
                u.us[2] = f2bf(v.z * s); u.us[3] = f2bf(v.w * s);
                *(uint2*)&tile[il][wq << 2] = u.u2;
            }
            __syncthreads();
            union { unsigned short us[8]; uint4 v; } u;
#pragma unroll
            for (int j = 0; j < 8; ++j) u.us[j] = tile[ib + j][wb];
            *(uint4*)(xmod + (((size_t)(b * 66 + h + 1) * 66 + (wb + 1)) << 9) + i0 + ib) = u.v;
            __syncthreads();
        }
    } else if (bid < 384) {
        unsigned short* stg = (unsigned short*)shraw;
        int blk = bid - 256;
        int mt = blk >> 5, rem = blk & 31, ic = rem >> 1, half = rem & 1;
        int o_l = t >> 3, c8 = t & 7;
        const float4* src4 = (const float4*)(wsrc + (size_t)((mt << 7) + (half << 6) + o_l) * 4608 + ic * 288);
        int wsl = o_l >> 4, lm = o_l & 15;
#pragma unroll
        for (int q = 0; q < 9; ++q) {
            float4 v = src4[c8 + (q << 3)];
            int e0 = (c8 + (q << 3)) << 2;
#pragma unroll
            for (int c = 0; c < 4; ++c) {
                int e = e0 + c;
                int il = e / 9, r = e - il * 9;
                int lk = il >> 3, j = il & 7;
                float fv = (c == 0) ? v.x : (c == 1) ? v.y : (c == 2) ? v.z : v.w;
                stg[r * 2048 + wsl * 512 + ((lk << 4) + lm) * 8 + j] = f2bf(fv);
            }
        }
        __syncthreads();
        unsigned short* dst = wpk3 + (((size_t)(mt * 144 + ic * 9)) << 12) + (half << 11);
#pragma unroll
        for (int q5 = 0; q5 < 5; ++q5) {
            int v = (q5 << 9) + t;
            if (v < 2304) {
                int q = v >> 8, word = v & 255;
                *(uint4*)(dst + (q << 12) + word * 8) = *(const uint4*)(stg + v * 8);
            }
        }
    } else {
        int idx = (bid - 384) * 512 + t;
        int cell = idx >> 6, sub = idx & 63;
        int b = cell / 260, c = cell - b * 260;
        int row, col;
        if (c < 66)       { row = 0;  col = c; }
        else if (c < 132) { row = 65; col = c - 66; }
        else { int d = c - 132; row = 1 + (d >> 1); col = (d & 1) * 65; }
        uint4 z; z.x = z.y = z.z = z.w = 0u;
        *(uint4*)(xmod + (((size_t)(b * 66 + row) * 66 + col) << 9) + (sub << 3)) = z;
    }
}

// ---- k_conv: R19 structure with BK=64 periods. 2 LDS buffers x 34816 B (64 ch each,
// two 17408-B halves). ONE barrier + WAITV(8) per 18-step period (9 total vs 145).
// Next period's B (10 GLDS) issued at r==9, ~9 steps of flight. af waits compiler-
// tracked; at period top exactly af(r=16,17)=8 loads outstanding, B older -> WAITV(8).
__global__ __launch_bounds__(256, 2) void k_conv(const unsigned short* __restrict__ xmod,
                                                 const unsigned short* __restrict__ wpk3,
                                                 float* __restrict__ out) {
    __shared__ __attribute__((aligned(128))) unsigned char lds[2][34816];

    int bid = blockIdx.x;
    int swz = ((bid & 7) << 6) | (bid >> 3);
    int mt = swz >> 7, nt = swz & 127;
    int b = nt >> 5, h0 = (nt & 31) << 1;
    int m0 = mt << 7;
    int tid = threadIdx.x;
    int lane = tid & 63;
    int wv = tid >> 6;
    int wave_m = wv & 1, wave_n = wv >> 1;
    int lm = lane & 15, lk = lane >> 4;

    const unsigned char* xq = (const unsigned char*)xmod;

    int bsrc[5];
#pragma unroll
    for (int q = 0; q < 5; ++q) {
        int c = q * 256 + tid; if (c > 1055) c = 1055;
        int cl = c >> 2, sub = c & 3;
        int row = cl / 66, col = cl - row * 66;
        int sub2 = sub ^ ((col >> 1) & 3);
        bsrc[q] = ((b * 66 + h0 + row) * 66 + col) * 1024 + (sub2 << 4);
    }

    int boff[4][3];
#pragma unroll
    for (int fn = 0; fn < 4; ++fn) {
        int nl = (wave_n << 6) + (fn << 4) + lm;
        int hl = nl >> 6, w = nl & 63;
#pragma unroll
        for (int kw = 0; kw < 3; ++kw) {
            int col = w + kw;
            boff[fn][kw] = hl * 4224 + col * 64 + ((lk ^ ((col >> 1) & 3)) << 4);
        }
    }

    const unsigned short* abase = wpk3 + ((size_t)mt * 144) * 4096 + ((wave_m << 2) << 9) + (lane << 3);

    f32x4 acc[4][4] = {};
    bf16x8 af[3][4];
    bf16x8 bfr[2][4];

    // ---- prologue: issue B period 0 (chunks 0,1 -> both halves of buf0), af s=0,1 ----
    {
        unsigned char* bd = &lds[0][0] + wv * 1024;
#pragma unroll
        for (int half = 0; half < 2; ++half) {
#pragma unroll
            for (int q = 0; q < 5; ++q) {
                if (q * 256 + tid < 1056)
                    GLDS(xq + bsrc[q] + half * 64, bd + half * 17408 + q * 4096);
            }
        }
    }
#pragma unroll
    for (int s = 0; s < 2; ++s)
#pragma unroll
        for (int fm = 0; fm < 4; ++fm)
            af[s][fm] = *(const bf16x8*)(abase + s * 4096 + fm * 512);
    WAITV(0);
    __builtin_amdgcn_s_barrier();
    MEMF();

#pragma unroll 1
    for (int pd = 0; pd < 8; ++pd) {
        const unsigned char* Bb = &lds[pd & 1][0];
        unsigned char* Bn = &lds[(pd + 1) & 1][0];
#pragma unroll
        for (int r = 0; r < 18; ++r) {
            if (r == 0) {
                if (pd) {
                    // af(r=16),af(r=17) = 8 outstanding; B batch (r==9 prev) is older
                    WAITV(8);
                    __builtin_amdgcn_s_barrier();
                    MEMF();
                }
                // own-step bfr: tap 0, half 0
#pragma unroll
                for (int fn = 0; fn < 4; ++fn)
                    bfr[0][fn] = *(const bf16x8*)(Bb + boff[fn][0]);
            }
            int s = pd * 18 + r;
            // issue af(s+2) -> slot (r+2)%3  (18%3==0: period-invariant; 16KB tail slack)
            {
                const unsigned short* ap = abase + (size_t)(s + 2) * 4096;
#pragma unroll
                for (int fm = 0; fm < 4; ++fm)
                    af[(r + 2) % 3][fm] = *(const bf16x8*)(ap + fm * 512);
            }
            if (r == 9) {   // issue next period's 64-ch B (pd==7: harmless dummy)
                int icb = (pd + 1) << 7;   // (pd+1)*2 chunks * 64 B
                unsigned char* bd = Bn + wv * 1024;
#pragma unroll
                for (int half = 0; half < 2; ++half) {
#pragma unroll
                    for (int q = 0; q < 5; ++q) {
                        if (q * 256 + tid < 1056)
                            GLDS(xq + bsrc[q] + icb + half * 64, bd + half * 17408 + q * 4096);
                    }
                }
            }
            // prefetch NEXT step's bfr (skip at r==17: next period's data loaded at top)
            if (r < 17) {
                int r1 = r + 1;
                int rr1 = (r1 >= 9) ? (r1 - 9) : r1;
                int kh1 = rr1 / 3, kw1 = rr1 - kh1 * 3;
                int hoff1 = (r1 >= 9) ? 17408 : 0;
#pragma unroll
                for (int fn = 0; fn < 4; ++fn)
                    bfr[(r + 1) & 1][fn] = *(const bf16x8*)(Bb + hoff1 + boff[fn][kw1] + kh1 * 4224);
            }
            __builtin_amdgcn_s_setprio(1);
#pragma unroll
            for (int fm = 0; fm < 4; ++fm)
#pragma unroll
                for (int fn = 0; fn < 4; ++fn)
                    acc[fm][fn] = __builtin_amdgcn_mfma_f32_16x16x32_bf16(af[r % 3][fm], bfr[r & 1][fn], acc[fm][fn], 0, 0, 0);
            __builtin_amdgcn_s_setprio(0);
            MEMF();
        }
    }

#pragma unroll
    for (int fm = 0; fm < 4; ++fm) {
        int o = m0 + (wave_m << 6) + (fm << 4) + (lk << 2);
#pragma unroll
        for (int fn = 0; fn < 4; ++fn) {
            int nl = (wave_n << 6) + (fn << 4) + lm;
            int hl = nl >> 6, w = nl & 63;
            float* dst = out + ((((b << 9) + o) << 6) + (h0 + hl)) * 64 + w;
#pragma unroll
            for (int rr = 0; rr < 4; ++rr)
                dst[rr * 4096] = acc[fm][fn][rr];
        }
    }
}

extern "C" void kernel_launch(void* const* d_in, const int* in_sizes, int n_in,
                              void* d_out, int out_size, void* d_ws, size_t ws_size,
                              hipStream_t stream) {
    const float* x      = (const float*)d_in[0];
    const float* style  = (const float*)d_in[1];
    const float* weight = (const float*)d_in[2];
    const float* aff_w  = (const float*)d_in[3];
    const float* aff_b  = (const float*)d_in[4];
    float* out = (float*)d_out;

    unsigned short* xmod = (unsigned short*)d_ws;            // 17,842,176 B
    unsigned short* wpk3 = xmod + 8921088;                   // 4,718,592 B (+16KB tail slack)

    hipLaunchKernelGGL(k_pack, dim3(514), dim3(512), 0, stream,
                       x, style, aff_w, aff_b, weight, xmod, wpk3);
    hipLaunchKernelGGL(k_conv, dim3(512), dim3(256), 0, stream, xmod, wpk3, out);
}